// Round 6
// baseline (402.582 us; speedup 1.0000x reference)
//
#include <hip/hip_runtime.h>

#define D 128
#define KOUT 100
#define CHUNK 4096   // edges per pass-1 block

typedef __attribute__((ext_vector_type(8))) short short8;
typedef __attribute__((ext_vector_type(4))) float floatx4;

// ---------------- bf16 pack/unpack helpers ----------------
__device__ inline float bf_lo(unsigned int u) { return __uint_as_float(u << 16); }
__device__ inline float bf_hi(unsigned int u) { return __uint_as_float(u & 0xFFFF0000u); }

__device__ inline unsigned int bf_round(float a) {      // f32 -> bf16 bits (RNE)
    unsigned int ua = __float_as_uint(a);
    return (ua + 0x7FFFu + ((ua >> 16) & 1u)) >> 16;
}
__device__ inline unsigned int pack_bf(float a, float b) {
    return bf_round(a) | (bf_round(b) << 16);
}

// ---------------- CSR build: two-pass bucket radix partition ----------------
// bucket = dst >> 8; packed record: bits[23:0]=src, bits[31:24]=dst&255

__launch_bounds__(256)
__global__ void bucket_pass1(const int* __restrict__ ei, int E, int nbuck, int cap,
                             int* __restrict__ bcur, unsigned int* __restrict__ bdata) {
    __shared__ int hist[256];
    __shared__ int sc[256];
    __shared__ int pfx[257];
    __shared__ int cur[256];
    __shared__ int gbase[256];
    __shared__ unsigned int lbuf[CHUNK];   // 16 KB

    int tid = threadIdx.x;
    int base = blockIdx.x * CHUNK;
    int cnt = E - base; if (cnt > CHUNK) cnt = CHUNK;

    hist[tid] = 0;
    __syncthreads();

    int src[CHUNK / 256];
    int dst[CHUNK / 256];
#pragma unroll
    for (int q = 0; q < CHUNK / 256; q++) {
        int li = tid + q * 256;
        if (li < cnt) {
            src[q] = ei[base + li];
            dst[q] = ei[E + base + li];
            atomicAdd(&hist[dst[q] >> 8], 1);
        }
    }
    __syncthreads();

    int v = hist[tid];
    sc[tid] = v;
    __syncthreads();
    for (int off = 1; off < 256; off <<= 1) {
        int t = (tid >= off) ? sc[tid - off] : 0;
        __syncthreads();
        sc[tid] += t;
        __syncthreads();
    }
    int excl = sc[tid] - v;
    pfx[tid] = excl;
    cur[tid] = excl;
    gbase[tid] = 0;
    if (tid < nbuck && v > 0) gbase[tid] = atomicAdd(&bcur[tid], v);
    if (tid == 0) pfx[nbuck] = cnt;
    __syncthreads();

#pragma unroll
    for (int q = 0; q < CHUNK / 256; q++) {
        int li = tid + q * 256;
        if (li < cnt) {
            int b = dst[q] >> 8;
            int p = atomicAdd(&cur[b], 1);
            lbuf[p] = (unsigned int)src[q] | ((unsigned int)(dst[q] & 255) << 24);
        }
    }
    __syncthreads();

    for (int p = tid; p < cnt; p += 256) {
        int lo = 0, hi = nbuck - 1;
        while (lo < hi) {
            int mid = (lo + hi + 1) >> 1;
            if (pfx[mid] <= p) lo = mid; else hi = mid - 1;
        }
        int b = lo;
        bdata[(size_t)b * cap + gbase[b] + (p - pfx[b])] = lbuf[p];
    }
}

__launch_bounds__(256)
__global__ void bucket_deg(const unsigned int* __restrict__ bdata, const int* __restrict__ bcur,
                           int cap, int* __restrict__ deg, float* __restrict__ dinv, int n) {
    __shared__ int hist[256];
    int b = blockIdx.x, tid = threadIdx.x;
    hist[tid] = 0;
    __syncthreads();
    int cnt = bcur[b];
    const unsigned int* p = bdata + (size_t)b * cap;
    for (int e = tid; e < cnt; e += 256) atomicAdd(&hist[p[e] >> 24], 1);
    __syncthreads();
    int node = b * 256 + tid;
    if (node < n) {
        int d = hist[tid] + 1;
        deg[node] = d;
        dinv[node] = rsqrtf((float)d);
    }
}

// single-block exclusive scan of (deg-1) -> rowptr
__launch_bounds__(256)
__global__ void scan_kernel(const int* __restrict__ deg, int* __restrict__ rowptr, int n) {
    __shared__ int sc[256];
    int tid = threadIdx.x;
    int chunk = (n + 255) / 256;
    int i0 = tid * chunk;
    int i1 = i0 + chunk; if (i1 > n) i1 = n;
    int sum = 0;
    for (int i = i0; i < i1; i++) sum += deg[i] - 1;
    sc[tid] = sum;
    __syncthreads();
    for (int off = 1; off < 256; off <<= 1) {
        int t = (tid >= off) ? sc[tid - off] : 0;
        __syncthreads();
        sc[tid] += t;
        __syncthreads();
    }
    int run = sc[tid] - sum;
    for (int i = i0; i < i1; i++) { rowptr[i] = run; run += deg[i] - 1; }
}

__launch_bounds__(256)
__global__ void bucket_scatter(const unsigned int* __restrict__ bdata, const int* __restrict__ bcur,
                               int cap, const int* __restrict__ rowptr, int* __restrict__ csr, int n) {
    __shared__ int cur[256];
    int b = blockIdx.x, tid = threadIdx.x;
    int node = b * 256 + tid;
    cur[tid] = (node < n) ? rowptr[node] : 0;
    __syncthreads();
    int cnt = bcur[b];
    const unsigned int* p = bdata + (size_t)b * cap;
    for (int e = tid; e < cnt; e += 256) {
        unsigned int u = p[e];
        int pos = atomicAdd(&cur[u >> 24], 1);
        csr[pos] = (int)(u & 0xFFFFFFu);
    }
}

// ---------------- Weight prep: f32 -> bf16 MFMA B-fragment order ----------------
// Wfrag[(kt*8+ct)*64 + lane][j] = W[kt*32 + (lane>>4)*8 + j][ct*16 + (lane&15)]

__global__ void prep_frag_kernel(const float* __restrict__ W1, const float* __restrict__ W2,
                                 const float* __restrict__ Wa, const float* __restrict__ ba,
                                 unsigned short* __restrict__ Wf1, unsigned short* __restrict__ Wf2,
                                 unsigned short* __restrict__ WfA, float* __restrict__ bpad) {
    int idx = blockIdx.x * blockDim.x + threadIdx.x;
    if (idx < 3 * 16384) {
        int m = idx / 16384;
        int e = idx & 16383;
        int j = e & 7, lane = (e >> 3) & 63, ct = (e >> 9) & 7, kt = e >> 12;
        int k = kt * 32 + (lane >> 4) * 8 + j;
        int col = ct * 16 + (lane & 15);
        float val;
        unsigned short* dst;
        if (m == 0)      { val = W1[k * 128 + col]; dst = Wf1; }
        else if (m == 1) { val = W2[k * 128 + col]; dst = Wf2; }
        else             { val = (col < KOUT) ? Wa[k * KOUT + col] : 0.f; dst = WfA; }
        dst[e] = (unsigned short)bf_round(val);
    }
    if (idx < 128) bpad[idx] = (idx < KOUT) ? ba[idx] : 0.f;
}

// ---------------- MFMA GEMM: Y[n,128] = bf16(X[n,128]) @ Wfrag (+bias) ----------------
// block 256 thr = 4 waves; tile 64 rows x 128 cols; wave w: rows w*16..+15, all 128 cols.
// LDS: X tile as bf16 [64][136] halves (pad 8 to break b128 conflicts); reused as
// f32 out staging [64][130] for bf16-packed output path.

__launch_bounds__(256)
__global__ void gemm_mfma_kernel(const float* __restrict__ X, const unsigned short* __restrict__ Wf,
                                 const float* __restrict__ bias, void* __restrict__ Y,
                                 int nrows, int out_bf16) {
    __shared__ float lds_f[64 * 130];                      // 33280 B
    unsigned short* lds_h = (unsigned short*)lds_f;
    unsigned int* lds_u = (unsigned int*)lds_f;

    int tid = threadIdx.x;
    int w = tid >> 6, lane = tid & 63;
    int quad = lane >> 4, m16 = lane & 15;
    int r0 = blockIdx.x * 64;

    // stage X (f32 -> bf16) into LDS: thread = row (tid>>2), col group (tid&3)*32
    {
        int row = tid >> 2, cg = tid & 3;
        bool valid = (r0 + row) < nrows;
        const float4* Xr = (const float4*)X + (size_t)(r0 + row) * 32 + cg * 8;
#pragma unroll
        for (int j = 0; j < 8; j++) {
            float4 v = valid ? Xr[j] : make_float4(0.f, 0.f, 0.f, 0.f);
            int c = cg * 32 + j * 4;
            lds_u[row * 68 + (c >> 1)]     = pack_bf(v.x, v.y);
            lds_u[row * 68 + (c >> 1) + 1] = pack_bf(v.z, v.w);
        }
    }
    __syncthreads();

    floatx4 acc[8];
#pragma unroll
    for (int ct = 0; ct < 8; ct++) acc[ct] = (floatx4){0.f, 0.f, 0.f, 0.f};

    const short8* Wf8 = (const short8*)Wf;
#pragma unroll
    for (int kt = 0; kt < 4; kt++) {
        short8 a = *(const short8*)(lds_h + (w * 16 + m16) * 136 + kt * 32 + quad * 8);
#pragma unroll
        for (int ct = 0; ct < 8; ct++) {
            short8 b = Wf8[(kt * 8 + ct) * 64 + lane];
            acc[ct] = __builtin_amdgcn_mfma_f32_16x16x32_bf16(a, b, acc[ct], 0, 0, 0);
        }
    }

    if (out_bf16) {
        __syncthreads();   // done reading X tile; reuse LDS as f32 out staging [64][130]
#pragma unroll
        for (int ct = 0; ct < 8; ct++) {
#pragma unroll
            for (int r = 0; r < 4; r++) {
                int rl = w * 16 + quad * 4 + r;
                lds_f[rl * 130 + ct * 16 + m16] = acc[ct][r];
            }
        }
        __syncthreads();   // full barrier (LDS write -> read)
        unsigned int* Yb = (unsigned int*)Y;
        for (int r = 0; r < 16; r++) {
            int row = r0 + w * 16 + r;
            if (row < nrows) {
                float lo = lds_f[(w * 16 + r) * 130 + 2 * lane];
                float hi = lds_f[(w * 16 + r) * 130 + 2 * lane + 1];
                Yb[(size_t)row * 64 + lane] = pack_bf(lo, hi);
            }
        }
    } else {
        float* Yf = (float*)Y;
#pragma unroll
        for (int ct = 0; ct < 8; ct++) {
            float bb = bias ? bias[ct * 16 + m16] : 0.f;
#pragma unroll
            for (int r = 0; r < 4; r++) {
                int row = r0 + w * 16 + quad * 4 + r;
                if (row < nrows) Yf[(size_t)row * 128 + ct * 16 + m16] = acc[ct][r] + bb;
            }
        }
    }
}

// ---------------- Aggregate: O[i] = sum Hb[src]*dinv[src]*dinv[i] + Hb[i]*dinv^2 + b ----

__launch_bounds__(256)
__global__ void aggregate_kernel(const unsigned int* __restrict__ Hb, const int* __restrict__ csr,
                                 const int* __restrict__ rowptr, const int* __restrict__ deg,
                                 const float* __restrict__ dinv, const float* __restrict__ bias,
                                 float* __restrict__ O, int n, int do_relu) {
    int wid = threadIdx.x >> 6, lane = threadIdx.x & 63;
    int i = blockIdx.x * 4 + wid;
    if (i >= n) return;

    float di = dinv[i];
    float sl = di * di;
    unsigned int us = Hb[(size_t)i * 64 + lane];
    float ax = bf_lo(us) * sl;
    float ay = bf_hi(us) * sl;

    const int* cp = csr + rowptr[i];
    int cnt = deg[i] - 1;
    int e = 0;
    for (; e + 7 < cnt; e += 8) {
        int s[8];
        unsigned int u[8];
        float nn[8];
#pragma unroll
        for (int q = 0; q < 8; q++) s[q] = cp[e + q];
#pragma unroll
        for (int q = 0; q < 8; q++) {
            u[q] = Hb[(size_t)s[q] * 64 + lane];
            nn[q] = dinv[s[q]];
        }
#pragma unroll
        for (int q = 0; q < 8; q++) {
            float wgt = nn[q] * di;
            ax = fmaf(bf_lo(u[q]), wgt, ax);
            ay = fmaf(bf_hi(u[q]), wgt, ay);
        }
    }
    for (; e < cnt; e++) {
        int s0 = cp[e];
        unsigned int u0 = Hb[(size_t)s0 * 64 + lane];
        float wgt = dinv[s0] * di;
        ax = fmaf(bf_lo(u0), wgt, ax);
        ay = fmaf(bf_hi(u0), wgt, ay);
    }

    float2 b = ((const float2*)bias)[lane];
    ax += b.x; ay += b.y;
    if (do_relu) { ax = fmaxf(ax, 0.f); ay = fmaxf(ay, 0.f); }
    float2 o; o.x = ax; o.y = ay;
    ((float2*)O)[(size_t)i * 64 + lane] = o;
}

// ---------------- Softmax over K=100 (logits padded to 128) ----------------

__launch_bounds__(256)
__global__ void softmax_kernel(const float* __restrict__ L, float* __restrict__ O, int n) {
    int wid = threadIdx.x >> 6, lane = threadIdx.x & 63;
    int row = blockIdx.x * 4 + wid;
    if (row >= n) return;
    const float* lr = L + (size_t)row * 128;
    float v0 = (lane < KOUT) ? lr[lane] : -1e30f;
    float v1 = (lane + 64 < KOUT) ? lr[lane + 64] : -1e30f;
    float m = fmaxf(v0, v1);
    for (int off = 32; off > 0; off >>= 1) m = fmaxf(m, __shfl_xor(m, off));
    float e0 = (lane < KOUT) ? __expf(v0 - m) : 0.f;
    float e1 = (lane + 64 < KOUT) ? __expf(v1 - m) : 0.f;
    float s = e0 + e1;
    for (int off = 32; off > 0; off >>= 1) s += __shfl_xor(s, off);
    float inv = 1.f / s;
    if (lane < KOUT) O[(size_t)row * KOUT + lane] = e0 * inv;
    if (lane + 64 < KOUT) O[(size_t)row * KOUT + lane + 64] = e1 * inv;
}

// ---------------- launch ----------------

extern "C" void kernel_launch(void* const* d_in, const int* in_sizes, int n_in,
                              void* d_out, int out_size, void* d_ws, size_t ws_size,
                              hipStream_t stream) {
    const float* x  = (const float*)d_in[0];
    const int*   ei = (const int*)d_in[1];     // [2,E] int32
    const float* W1 = (const float*)d_in[2];
    const float* b1 = (const float*)d_in[3];
    const float* W2 = (const float*)d_in[4];
    const float* b2 = (const float*)d_in[5];
    const float* Wa = (const float*)d_in[6];
    const float* ba = (const float*)d_in[7];
    float* out = (float*)d_out;

    int N = in_sizes[0] / D;
    int E = in_sizes[1] / 2;

    int nbuck = (N + 255) >> 8;                       // 196 for N=50000
    int cap = ((E / nbuck) + 2048 + 63) & ~63;

    char* w = (char*)d_ws;
    size_t off = 0;
    auto carve = [&](size_t bytes) -> void* {
        void* p = w + off;
        off = (off + bytes + 255) & ~(size_t)255;
        return p;
    };
    int*   deg    = (int*)carve((size_t)N * 4);
    float* dinv   = (float*)carve((size_t)N * 4);
    int*   rowptr = (int*)carve((size_t)N * 4);
    int*   bcur   = (int*)carve(256 * 4);
    unsigned int* bdata = (unsigned int*)carve((size_t)nbuck * cap * 4);
    int*   csr    = (int*)carve((size_t)E * 4);
    unsigned short* Wf1 = (unsigned short*)carve(16384 * 2);
    unsigned short* Wf2 = (unsigned short*)carve(16384 * 2);
    unsigned short* WfA = (unsigned short*)carve(16384 * 2);
    float* bpad   = (float*)carve(512);
    unsigned int* Hb = (unsigned int*)carve((size_t)N * 64 * 4);   // bf16 row-major, 256 B/row
    float* bufB   = (float*)carve((size_t)N * D * 4);
    float* bufL   = (float*)carve((size_t)N * D * 4);
    (void)ws_size; (void)n_in; (void)out_size;

    int nbNode4 = (N + 3) / 4;
    int nbGemm = (N + 63) / 64;
    int nbP1 = (E + CHUNK - 1) / CHUNK;

    (void)hipMemsetAsync(bcur, 0, 256 * 4, stream);
    bucket_pass1<<<nbP1, 256, 0, stream>>>(ei, E, nbuck, cap, bcur, bdata);
    bucket_deg<<<nbuck, 256, 0, stream>>>(bdata, bcur, cap, deg, dinv, N);
    scan_kernel<<<1, 256, 0, stream>>>(deg, rowptr, N);
    bucket_scatter<<<nbuck, 256, 0, stream>>>(bdata, bcur, cap, rowptr, csr, N);
    prep_frag_kernel<<<192, 256, 0, stream>>>(W1, W2, Wa, ba, Wf1, Wf2, WfA, bpad);

    // layer 1: lin (MFMA, bf16 out) -> aggregate(+b1, relu) f32
    gemm_mfma_kernel<<<nbGemm, 256, 0, stream>>>(x, Wf1, nullptr, Hb, N, 1);
    aggregate_kernel<<<nbNode4, 256, 0, stream>>>(Hb, csr, rowptr, deg, dinv, b1, bufB, N, 1);
    // layer 2
    gemm_mfma_kernel<<<nbGemm, 256, 0, stream>>>(bufB, Wf2, nullptr, Hb, N, 1);
    aggregate_kernel<<<nbNode4, 256, 0, stream>>>(Hb, csr, rowptr, deg, dinv, b2, bufB, N, 0);
    // attention logits (f32, padded 128) + softmax
    gemm_mfma_kernel<<<nbGemm, 256, 0, stream>>>(bufB, WfA, bpad, bufL, N, 0);
    softmax_kernel<<<nbNode4, 256, 0, stream>>>(bufL, out, N);
}

// Round 7
// 329.195 us; speedup vs baseline: 1.2229x; 1.2229x over previous
//
#include <hip/hip_runtime.h>

#define D 128
#define KOUT 100
#define CHUNK 4096   // edges per pass-1 block

typedef __attribute__((ext_vector_type(8))) short short8;
typedef __attribute__((ext_vector_type(4))) float floatx4;

// ---------------- bf16 pack/unpack helpers ----------------
__device__ inline float bf_lo(unsigned int u) { return __uint_as_float(u << 16); }
__device__ inline float bf_hi(unsigned int u) { return __uint_as_float(u & 0xFFFF0000u); }

__device__ inline unsigned int bf_round(float a) {      // f32 -> bf16 bits (RNE)
    unsigned int ua = __float_as_uint(a);
    return (ua + 0x7FFFu + ((ua >> 16) & 1u)) >> 16;
}
__device__ inline unsigned int pack_bf(float a, float b) {
    return bf_round(a) | (bf_round(b) << 16);
}

// ---------------- CSR build: two-pass bucket radix partition ----------------
// bucket = dst >> 8; packed record: bits[23:0]=src, bits[31:24]=dst&255

__launch_bounds__(256)
__global__ void bucket_pass1(const int* __restrict__ ei, int E, int nbuck, int cap,
                             int* __restrict__ bcur, unsigned int* __restrict__ bdata) {
    __shared__ int hist[256];
    __shared__ int sc[256];
    __shared__ int pfx[257];
    __shared__ int cur[256];
    __shared__ int gbase[256];
    __shared__ unsigned int lbuf[CHUNK];   // 16 KB

    int tid = threadIdx.x;
    int base = blockIdx.x * CHUNK;
    int cnt = E - base; if (cnt > CHUNK) cnt = CHUNK;

    hist[tid] = 0;
    __syncthreads();

    int src[CHUNK / 256];
    int dst[CHUNK / 256];
#pragma unroll
    for (int q = 0; q < CHUNK / 256; q++) {
        int li = tid + q * 256;
        if (li < cnt) {
            src[q] = ei[base + li];
            dst[q] = ei[E + base + li];
            atomicAdd(&hist[dst[q] >> 8], 1);
        }
    }
    __syncthreads();

    int v = hist[tid];
    sc[tid] = v;
    __syncthreads();
    for (int off = 1; off < 256; off <<= 1) {
        int t = (tid >= off) ? sc[tid - off] : 0;
        __syncthreads();
        sc[tid] += t;
        __syncthreads();
    }
    int excl = sc[tid] - v;
    pfx[tid] = excl;
    cur[tid] = excl;
    gbase[tid] = 0;
    if (tid < nbuck && v > 0) gbase[tid] = atomicAdd(&bcur[tid], v);
    if (tid == 0) pfx[nbuck] = cnt;
    __syncthreads();

#pragma unroll
    for (int q = 0; q < CHUNK / 256; q++) {
        int li = tid + q * 256;
        if (li < cnt) {
            int b = dst[q] >> 8;
            int p = atomicAdd(&cur[b], 1);
            lbuf[p] = (unsigned int)src[q] | ((unsigned int)(dst[q] & 255) << 24);
        }
    }
    __syncthreads();

    for (int p = tid; p < cnt; p += 256) {
        int lo = 0, hi = nbuck - 1;
        while (lo < hi) {
            int mid = (lo + hi + 1) >> 1;
            if (pfx[mid] <= p) lo = mid; else hi = mid - 1;
        }
        int b = lo;
        bdata[(size_t)b * cap + gbase[b] + (p - pfx[b])] = lbuf[p];
    }
}

__launch_bounds__(256)
__global__ void bucket_deg(const unsigned int* __restrict__ bdata, const int* __restrict__ bcur,
                           int cap, int* __restrict__ deg, float* __restrict__ dinv, int n) {
    __shared__ int hist[256];
    int b = blockIdx.x, tid = threadIdx.x;
    hist[tid] = 0;
    __syncthreads();
    int cnt = bcur[b];
    const unsigned int* p = bdata + (size_t)b * cap;
    for (int e = tid; e < cnt; e += 256) atomicAdd(&hist[p[e] >> 24], 1);
    __syncthreads();
    int node = b * 256 + tid;
    if (node < n) {
        int d = hist[tid] + 1;
        deg[node] = d;
        dinv[node] = rsqrtf((float)d);
    }
}

// multi-block exclusive scan of (deg-1) -> rowptr, 1024 elems per block
__global__ void scan_block_kernel(const int* __restrict__ deg, int* __restrict__ rowptr,
                                  int* __restrict__ bsums, int n) {
    __shared__ int sd[256];
    int tid = threadIdx.x;
    int base = blockIdx.x * 1024 + tid * 4;
    int v[4];
    int sum = 0;
#pragma unroll
    for (int q = 0; q < 4; q++) {
        int idx = base + q;
        int c = (idx < n) ? (deg[idx] - 1) : 0;
        v[q] = sum;
        sum += c;
    }
    sd[tid] = sum;
    __syncthreads();
    for (int off = 1; off < 256; off <<= 1) {
        int t = (tid >= off) ? sd[tid - off] : 0;
        __syncthreads();
        sd[tid] += t;
        __syncthreads();
    }
    int excl = sd[tid] - sum;
#pragma unroll
    for (int q = 0; q < 4; q++) {
        int idx = base + q;
        if (idx < n) rowptr[idx] = excl + v[q];
    }
    if (tid == 255) bsums[blockIdx.x] = sd[255];
}

__global__ void scan_total_kernel(int* __restrict__ bsums, int nb) {
    if (threadIdx.x == 0 && blockIdx.x == 0) {
        int run = 0;
        for (int b = 0; b < nb; b++) { int t = bsums[b]; bsums[b] = run; run += t; }
    }
}

__global__ void scan_add_kernel(int* __restrict__ rowptr, const int* __restrict__ bsums, int n) {
    int i = blockIdx.x * blockDim.x + threadIdx.x;
    if (i < n) rowptr[i] += bsums[i >> 10];
}

__launch_bounds__(256)
__global__ void bucket_scatter(const unsigned int* __restrict__ bdata, const int* __restrict__ bcur,
                               int cap, const int* __restrict__ rowptr, int* __restrict__ csr, int n) {
    __shared__ int cur[256];
    int b = blockIdx.x, tid = threadIdx.x;
    int node = b * 256 + tid;
    cur[tid] = (node < n) ? rowptr[node] : 0;
    __syncthreads();
    int cnt = bcur[b];
    const unsigned int* p = bdata + (size_t)b * cap;
    for (int e = tid; e < cnt; e += 256) {
        unsigned int u = p[e];
        int pos = atomicAdd(&cur[u >> 24], 1);
        csr[pos] = (int)(u & 0xFFFFFFu);
    }
}

// ---------------- Weight prep: f32 -> bf16 MFMA B-fragment order ----------------
// Wfrag[(kt*8+ct)*64 + lane][j] = W[kt*32 + (lane>>4)*8 + j][ct*16 + (lane&15)]

__global__ void prep_frag_kernel(const float* __restrict__ W1, const float* __restrict__ W2,
                                 const float* __restrict__ Wa, const float* __restrict__ ba,
                                 unsigned short* __restrict__ Wf1, unsigned short* __restrict__ Wf2,
                                 unsigned short* __restrict__ WfA, float* __restrict__ bpad) {
    int idx = blockIdx.x * blockDim.x + threadIdx.x;
    if (idx < 3 * 16384) {
        int m = idx / 16384;
        int e = idx & 16383;
        int j = e & 7, lane = (e >> 3) & 63, ct = (e >> 9) & 7, kt = e >> 12;
        int k = kt * 32 + (lane >> 4) * 8 + j;
        int col = ct * 16 + (lane & 15);
        float val;
        unsigned short* dst;
        if (m == 0)      { val = W1[k * 128 + col]; dst = Wf1; }
        else if (m == 1) { val = W2[k * 128 + col]; dst = Wf2; }
        else             { val = (col < KOUT) ? Wa[k * KOUT + col] : 0.f; dst = WfA; }
        dst[e] = (unsigned short)bf_round(val);
    }
    if (idx < 128) bpad[idx] = (idx < KOUT) ? ba[idx] : 0.f;
}

// ---------------- MFMA GEMM: Y[n,128] = bf16(X[n,128]) @ Wfrag (+bias) ----------------
// block 256 thr = 4 waves; tile 64 rows x 128 cols; wave w: rows w*16..+15, all 128 cols.

__launch_bounds__(256)
__global__ void gemm_mfma_kernel(const float* __restrict__ X, const unsigned short* __restrict__ Wf,
                                 const float* __restrict__ bias, void* __restrict__ Y,
                                 int nrows, int out_bf16) {
    __shared__ float lds_f[64 * 130];                      // 33280 B
    unsigned short* lds_h = (unsigned short*)lds_f;
    unsigned int* lds_u = (unsigned int*)lds_f;

    int tid = threadIdx.x;
    int w = tid >> 6, lane = tid & 63;
    int quad = lane >> 4, m16 = lane & 15;
    int r0 = blockIdx.x * 64;

    // stage X (f32 -> bf16) into LDS: thread = row (tid>>2), col group (tid&3)*32
    {
        int row = tid >> 2, cg = tid & 3;
        bool valid = (r0 + row) < nrows;
        const float4* Xr = (const float4*)X + (size_t)(r0 + row) * 32 + cg * 8;
#pragma unroll
        for (int j = 0; j < 8; j++) {
            float4 v = valid ? Xr[j] : make_float4(0.f, 0.f, 0.f, 0.f);
            int c = cg * 32 + j * 4;
            lds_u[row * 68 + (c >> 1)]     = pack_bf(v.x, v.y);
            lds_u[row * 68 + (c >> 1) + 1] = pack_bf(v.z, v.w);
        }
    }
    __syncthreads();

    floatx4 acc[8];
#pragma unroll
    for (int ct = 0; ct < 8; ct++) acc[ct] = (floatx4){0.f, 0.f, 0.f, 0.f};

    const short8* Wf8 = (const short8*)Wf;
#pragma unroll
    for (int kt = 0; kt < 4; kt++) {
        short8 a = *(const short8*)(lds_h + (w * 16 + m16) * 136 + kt * 32 + quad * 8);
#pragma unroll
        for (int ct = 0; ct < 8; ct++) {
            short8 b = Wf8[(kt * 8 + ct) * 64 + lane];
            acc[ct] = __builtin_amdgcn_mfma_f32_16x16x32_bf16(a, b, acc[ct], 0, 0, 0);
        }
    }

    if (out_bf16) {
        __syncthreads();   // done reading X tile; reuse LDS as f32 out staging [64][130]
#pragma unroll
        for (int ct = 0; ct < 8; ct++) {
#pragma unroll
            for (int r = 0; r < 4; r++) {
                int rl = w * 16 + quad * 4 + r;
                lds_f[rl * 130 + ct * 16 + m16] = acc[ct][r];
            }
        }
        __syncthreads();
        unsigned int* Yb = (unsigned int*)Y;
        for (int r = 0; r < 16; r++) {
            int row = r0 + w * 16 + r;
            if (row < nrows) {
                float lo = lds_f[(w * 16 + r) * 130 + 2 * lane];
                float hi = lds_f[(w * 16 + r) * 130 + 2 * lane + 1];
                Yb[(size_t)row * 64 + lane] = pack_bf(lo, hi);
            }
        }
    } else {
        float* Yf = (float*)Y;
#pragma unroll
        for (int ct = 0; ct < 8; ct++) {
            float bb = bias ? bias[ct * 16 + m16] : 0.f;
#pragma unroll
            for (int r = 0; r < 4; r++) {
                int row = r0 + w * 16 + quad * 4 + r;
                if (row < nrows) Yf[(size_t)row * 128 + ct * 16 + m16] = acc[ct][r] + bb;
            }
        }
    }
}

// ---------------- Aggregate: O[i] = sum Hb[src]*dinv[src]*dinv[i] + Hb[i]*dinv^2 + b ----

__launch_bounds__(256)
__global__ void aggregate_kernel(const unsigned int* __restrict__ Hb, const int* __restrict__ csr,
                                 const int* __restrict__ rowptr, const int* __restrict__ deg,
                                 const float* __restrict__ dinv, const float* __restrict__ bias,
                                 float* __restrict__ O, int n, int do_relu) {
    int wid = threadIdx.x >> 6, lane = threadIdx.x & 63;
    int i = blockIdx.x * 4 + wid;
    if (i >= n) return;

    float di = dinv[i];
    float sl = di * di;
    unsigned int us = Hb[(size_t)i * 64 + lane];
    float ax = bf_lo(us) * sl;
    float ay = bf_hi(us) * sl;

    const int* cp = csr + rowptr[i];
    int cnt = deg[i] - 1;
    int e = 0;
    for (; e + 7 < cnt; e += 8) {
        int s[8];
        unsigned int u[8];
        float nn[8];
#pragma unroll
        for (int q = 0; q < 8; q++) s[q] = cp[e + q];
#pragma unroll
        for (int q = 0; q < 8; q++) {
            u[q] = Hb[(size_t)s[q] * 64 + lane];
            nn[q] = dinv[s[q]];
        }
#pragma unroll
        for (int q = 0; q < 8; q++) {
            float wgt = nn[q] * di;
            ax = fmaf(bf_lo(u[q]), wgt, ax);
            ay = fmaf(bf_hi(u[q]), wgt, ay);
        }
    }
    for (; e < cnt; e++) {
        int s0 = cp[e];
        unsigned int u0 = Hb[(size_t)s0 * 64 + lane];
        float wgt = dinv[s0] * di;
        ax = fmaf(bf_lo(u0), wgt, ax);
        ay = fmaf(bf_hi(u0), wgt, ay);
    }

    float2 b = ((const float2*)bias)[lane];
    ax += b.x; ay += b.y;
    if (do_relu) { ax = fmaxf(ax, 0.f); ay = fmaxf(ay, 0.f); }
    float2 o; o.x = ax; o.y = ay;
    ((float2*)O)[(size_t)i * 64 + lane] = o;
}

// ---------------- Softmax over K=100 (logits padded to 128) ----------------

__launch_bounds__(256)
__global__ void softmax_kernel(const float* __restrict__ L, float* __restrict__ O, int n) {
    int wid = threadIdx.x >> 6, lane = threadIdx.x & 63;
    int row = blockIdx.x * 4 + wid;
    if (row >= n) return;
    const float* lr = L + (size_t)row * 128;
    float v0 = (lane < KOUT) ? lr[lane] : -1e30f;
    float v1 = (lane + 64 < KOUT) ? lr[lane + 64] : -1e30f;
    float m = fmaxf(v0, v1);
    for (int off = 32; off > 0; off >>= 1) m = fmaxf(m, __shfl_xor(m, off));
    float e0 = (lane < KOUT) ? __expf(v0 - m) : 0.f;
    float e1 = (lane + 64 < KOUT) ? __expf(v1 - m) : 0.f;
    float s = e0 + e1;
    for (int off = 32; off > 0; off >>= 1) s += __shfl_xor(s, off);
    float inv = 1.f / s;
    if (lane < KOUT) O[(size_t)row * KOUT + lane] = e0 * inv;
    if (lane + 64 < KOUT) O[(size_t)row * KOUT + lane + 64] = e1 * inv;
}

// ---------------- launch ----------------

extern "C" void kernel_launch(void* const* d_in, const int* in_sizes, int n_in,
                              void* d_out, int out_size, void* d_ws, size_t ws_size,
                              hipStream_t stream) {
    const float* x  = (const float*)d_in[0];
    const int*   ei = (const int*)d_in[1];     // [2,E] int32
    const float* W1 = (const float*)d_in[2];
    const float* b1 = (const float*)d_in[3];
    const float* W2 = (const float*)d_in[4];
    const float* b2 = (const float*)d_in[5];
    const float* Wa = (const float*)d_in[6];
    const float* ba = (const float*)d_in[7];
    float* out = (float*)d_out;

    int N = in_sizes[0] / D;
    int E = in_sizes[1] / 2;

    int nbuck = (N + 255) >> 8;                       // 196 for N=50000
    int cap = ((E / nbuck) + 2048 + 63) & ~63;

    char* w = (char*)d_ws;
    size_t off = 0;
    auto carve = [&](size_t bytes) -> void* {
        void* p = w + off;
        off = (off + bytes + 255) & ~(size_t)255;
        return p;
    };
    int*   deg    = (int*)carve((size_t)N * 4);
    float* dinv   = (float*)carve((size_t)N * 4);
    int*   rowptr = (int*)carve((size_t)N * 4);
    int*   bsums  = (int*)carve(1024);
    int*   bcur   = (int*)carve(256 * 4);
    unsigned int* bdata = (unsigned int*)carve((size_t)nbuck * cap * 4);
    int*   csr    = (int*)carve((size_t)E * 4);
    unsigned short* Wf1 = (unsigned short*)carve(16384 * 2);
    unsigned short* Wf2 = (unsigned short*)carve(16384 * 2);
    unsigned short* WfA = (unsigned short*)carve(16384 * 2);
    float* bpad   = (float*)carve(512);
    unsigned int* Hb = (unsigned int*)carve((size_t)N * 64 * 4);   // bf16 row-major, 256 B/row
    float* bufB   = (float*)carve((size_t)N * D * 4);
    float* bufL   = (float*)carve((size_t)N * D * 4);
    (void)ws_size; (void)n_in; (void)out_size;

    int nbN = (N + 255) / 256;
    int nbScan = (N + 1023) / 1024;
    int nbNode4 = (N + 3) / 4;
    int nbGemm = (N + 63) / 64;
    int nbP1 = (E + CHUNK - 1) / CHUNK;

    (void)hipMemsetAsync(bcur, 0, 256 * 4, stream);
    bucket_pass1<<<nbP1, 256, 0, stream>>>(ei, E, nbuck, cap, bcur, bdata);
    bucket_deg<<<nbuck, 256, 0, stream>>>(bdata, bcur, cap, deg, dinv, N);
    scan_block_kernel<<<nbScan, 256, 0, stream>>>(deg, rowptr, bsums, N);
    scan_total_kernel<<<1, 64, 0, stream>>>(bsums, nbScan);
    scan_add_kernel<<<nbN, 256, 0, stream>>>(rowptr, bsums, N);
    bucket_scatter<<<nbuck, 256, 0, stream>>>(bdata, bcur, cap, rowptr, csr, N);
    prep_frag_kernel<<<192, 256, 0, stream>>>(W1, W2, Wa, ba, Wf1, Wf2, WfA, bpad);

    // layer 1: lin (MFMA, bf16 out) -> aggregate(+b1, relu) f32
    gemm_mfma_kernel<<<nbGemm, 256, 0, stream>>>(x, Wf1, nullptr, Hb, N, 1);
    aggregate_kernel<<<nbNode4, 256, 0, stream>>>(Hb, csr, rowptr, deg, dinv, b1, bufB, N, 1);
    // layer 2
    gemm_mfma_kernel<<<nbGemm, 256, 0, stream>>>(bufB, Wf2, nullptr, Hb, N, 1);
    aggregate_kernel<<<nbNode4, 256, 0, stream>>>(Hb, csr, rowptr, deg, dinv, b2, bufB, N, 0);
    // attention logits (f32, padded 128) + softmax
    gemm_mfma_kernel<<<nbGemm, 256, 0, stream>>>(bufB, WfA, bpad, bufL, N, 0);
    softmax_kernel<<<nbNode4, 256, 0, stream>>>(bufL, out, N);
}

// Round 8
// 277.396 us; speedup vs baseline: 1.4513x; 1.1867x over previous
//
#include <hip/hip_runtime.h>

#define D 128
#define KOUT 100
#define CHUNK 4096   // edges per pass-1 block
#define BCAP 12288   // max edges per bucket held in LDS (cap must be <= this)

typedef __attribute__((ext_vector_type(8))) short short8;
typedef __attribute__((ext_vector_type(4))) float floatx4;

// ---------------- bf16 pack/unpack helpers ----------------
__device__ inline float bf_lo(unsigned int u) { return __uint_as_float(u << 16); }
__device__ inline float bf_hi(unsigned int u) { return __uint_as_float(u & 0xFFFF0000u); }

__device__ inline unsigned int bf_round(float a) {      // f32 -> bf16 bits (RNE)
    unsigned int ua = __float_as_uint(a);
    return (ua + 0x7FFFu + ((ua >> 16) & 1u)) >> 16;
}
__device__ inline unsigned int pack_bf(float a, float b) {
    return bf_round(a) | (bf_round(b) << 16);
}

// ---------------- CSR build pass 1: bucket radix partition ----------------
// bucket = dst >> 8; packed record: bits[23:0]=src, bits[31:24]=dst&255

__launch_bounds__(256)
__global__ void bucket_pass1(const int* __restrict__ ei, int E, int nbuck, int cap,
                             int* __restrict__ bcur, unsigned int* __restrict__ bdata) {
    __shared__ int hist[256];
    __shared__ int sc[256];
    __shared__ int pfx[256];
    __shared__ int cur[256];
    __shared__ int gbase[256];
    __shared__ unsigned int lbuf[CHUNK];      // 16 KB
    __shared__ unsigned char bkt[CHUNK];      // 4 KB: bucket id per lbuf slot

    int tid = threadIdx.x;
    int base = blockIdx.x * CHUNK;
    int cnt = E - base; if (cnt > CHUNK) cnt = CHUNK;

    hist[tid] = 0;
    __syncthreads();

    int src[CHUNK / 256];
    int dst[CHUNK / 256];
#pragma unroll
    for (int q = 0; q < CHUNK / 256; q++) {
        int li = tid + q * 256;
        if (li < cnt) {
            src[q] = ei[base + li];
            dst[q] = ei[E + base + li];
            atomicAdd(&hist[dst[q] >> 8], 1);
        }
    }
    __syncthreads();

    int v = hist[tid];
    sc[tid] = v;
    __syncthreads();
    for (int off = 1; off < 256; off <<= 1) {
        int t = (tid >= off) ? sc[tid - off] : 0;
        __syncthreads();
        sc[tid] += t;
        __syncthreads();
    }
    int excl = sc[tid] - v;
    pfx[tid] = excl;
    cur[tid] = excl;
    gbase[tid] = 0;
    if (tid < nbuck && v > 0) gbase[tid] = atomicAdd(&bcur[tid], v);
    __syncthreads();

#pragma unroll
    for (int q = 0; q < CHUNK / 256; q++) {
        int li = tid + q * 256;
        if (li < cnt) {
            int b = dst[q] >> 8;
            int p = atomicAdd(&cur[b], 1);
            lbuf[p] = (unsigned int)src[q] | ((unsigned int)(dst[q] & 255) << 24);
            bkt[p] = (unsigned char)b;
        }
    }
    __syncthreads();

    // coalesced run writes; bucket id from LDS (no binary search)
    for (int p = tid; p < cnt; p += 256) {
        int b = bkt[p];
        bdata[(size_t)b * cap + gbase[b] + (p - pfx[b])] = lbuf[p];
    }
}

// ---------------- CSR build pass 2 (fused): deg + dinv + rowptr + scatter ----------------
// one block per bucket; bucket records held in LDS; global base via on-the-fly bcur scan.

__launch_bounds__(256)
__global__ void bucket_build(const unsigned int* __restrict__ bdata, const int* __restrict__ bcur,
                             int cap, int* __restrict__ deg, float* __restrict__ dinv,
                             int* __restrict__ rowptr, int* __restrict__ csr, int n, int nbuck) {
    __shared__ unsigned int lbuf[BCAP];   // 48 KB
    __shared__ int cnts[256];
    __shared__ int sc[256];
    __shared__ int cur[256];
    __shared__ int bbase;

    int b = blockIdx.x, tid = threadIdx.x;
    if (tid == 0) bbase = 0;
    cnts[tid] = 0;
    __syncthreads();

    // sum of bucket counts before b
    int part = 0;
    for (int t = tid; t < b; t += 256) part += bcur[t];
#pragma unroll
    for (int off = 32; off > 0; off >>= 1) part += __shfl_down(part, off);
    if ((tid & 63) == 0 && part != 0) atomicAdd(&bbase, part);

    int cnt = bcur[b];
    for (int e = tid; e < cnt; e += 256) {
        unsigned int u = bdata[(size_t)b * cap + e];
        lbuf[e] = u;
        atomicAdd(&cnts[u >> 24], 1);
    }
    __syncthreads();

    int v = cnts[tid];
    sc[tid] = v;
    __syncthreads();
    for (int off = 1; off < 256; off <<= 1) {
        int t = (tid >= off) ? sc[tid - off] : 0;
        __syncthreads();
        sc[tid] += t;
        __syncthreads();
    }
    int gstart = bbase + (sc[tid] - v);
    int node = b * 256 + tid;
    if (node < n) {
        deg[node] = v + 1;
        dinv[node] = rsqrtf((float)(v + 1));
        rowptr[node] = gstart;
    }
    cur[tid] = gstart;
    __syncthreads();

    for (int e = tid; e < cnt; e += 256) {
        unsigned int u = lbuf[e];
        int pos = atomicAdd(&cur[u >> 24], 1);
        csr[pos] = (int)(u & 0xFFFFFFu);
    }
}

// ---------------- Weight prep: f32 -> bf16 MFMA B-fragment order ----------------
// Wfrag[(kt*8+ct)*64 + lane][j] = W[kt*32 + (lane>>4)*8 + j][ct*16 + (lane&15)]

__global__ void prep_frag_kernel(const float* __restrict__ W1, const float* __restrict__ W2,
                                 const float* __restrict__ Wa, const float* __restrict__ ba,
                                 unsigned short* __restrict__ Wf1, unsigned short* __restrict__ Wf2,
                                 unsigned short* __restrict__ WfA, float* __restrict__ bpad) {
    int idx = blockIdx.x * blockDim.x + threadIdx.x;
    if (idx < 3 * 16384) {
        int m = idx / 16384;
        int e = idx & 16383;
        int j = e & 7, lane = (e >> 3) & 63, ct = (e >> 9) & 7, kt = e >> 12;
        int k = kt * 32 + (lane >> 4) * 8 + j;
        int col = ct * 16 + (lane & 15);
        float val;
        unsigned short* dst;
        if (m == 0)      { val = W1[k * 128 + col]; dst = Wf1; }
        else if (m == 1) { val = W2[k * 128 + col]; dst = Wf2; }
        else             { val = (col < KOUT) ? Wa[k * KOUT + col] : 0.f; dst = WfA; }
        dst[e] = (unsigned short)bf_round(val);
    }
    if (idx < 128) bpad[idx] = (idx < KOUT) ? ba[idx] : 0.f;
}

// ---------------- MFMA GEMM ----------------
// block 256 = 4 waves; tile 64 rows x 128 cols; wave w: rows w*16..+15.
// in_bf16: A-fragments read directly from packed-bf16 global rows (no staging).
// out_mode 1: packed-bf16 rows (via LDS transpose). out_mode 2: +bias, softmax over
// first KOUT cols, f32 [nrows, KOUT] output.

__launch_bounds__(256)
__global__ void gemm_mfma_kernel(const void* __restrict__ Xin, const unsigned short* __restrict__ Wf,
                                 const float* __restrict__ bias, void* __restrict__ Y,
                                 int nrows, int in_bf16, int out_mode) {
    __shared__ float lds_f[64 * 130];                      // 33280 B
    unsigned short* lds_h = (unsigned short*)lds_f;
    unsigned int* lds_u = (unsigned int*)lds_f;

    int tid = threadIdx.x;
    int w = tid >> 6, lane = tid & 63;
    int quad = lane >> 4, m16 = lane & 15;
    int r0 = blockIdx.x * 64;

    if (!in_bf16) {
        // stage X (f32 -> bf16) into LDS: thread = row (tid>>2), col group (tid&3)*32
        int row = tid >> 2, cg = tid & 3;
        bool valid = (r0 + row) < nrows;
        const float4* Xr = (const float4*)Xin + (size_t)(r0 + row) * 32 + cg * 8;
#pragma unroll
        for (int j = 0; j < 8; j++) {
            float4 v = valid ? Xr[j] : make_float4(0.f, 0.f, 0.f, 0.f);
            int c = cg * 32 + j * 4;
            lds_u[row * 68 + (c >> 1)]     = pack_bf(v.x, v.y);
            lds_u[row * 68 + (c >> 1) + 1] = pack_bf(v.z, v.w);
        }
        __syncthreads();
    }

    floatx4 acc[8];
#pragma unroll
    for (int ct = 0; ct < 8; ct++) acc[ct] = (floatx4){0.f, 0.f, 0.f, 0.f};

    int arow = r0 + w * 16 + m16;
    if (arow > nrows - 1) arow = nrows - 1;
    const unsigned int* Xb = (const unsigned int*)Xin;

    const short8* Wf8 = (const short8*)Wf;
#pragma unroll
    for (int kt = 0; kt < 4; kt++) {
        short8 a;
        if (in_bf16) {
            a = *(const short8*)(Xb + (size_t)arow * 64 + kt * 16 + quad * 4);
        } else {
            a = *(const short8*)(lds_h + (w * 16 + m16) * 136 + kt * 32 + quad * 8);
        }
#pragma unroll
        for (int ct = 0; ct < 8; ct++) {
            short8 b = Wf8[(kt * 8 + ct) * 64 + lane];
            acc[ct] = __builtin_amdgcn_mfma_f32_16x16x32_bf16(a, b, acc[ct], 0, 0, 0);
        }
    }

    if (out_mode == 1) {
        __syncthreads();   // reuse LDS as f32 out staging [64][130]
#pragma unroll
        for (int ct = 0; ct < 8; ct++) {
#pragma unroll
            for (int r = 0; r < 4; r++) {
                int rl = w * 16 + quad * 4 + r;
                lds_f[rl * 130 + ct * 16 + m16] = acc[ct][r];
            }
        }
        __syncthreads();
        unsigned int* Yb = (unsigned int*)Y;
        for (int r = 0; r < 16; r++) {
            int row = r0 + w * 16 + r;
            if (row < nrows) {
                float lo = lds_f[(w * 16 + r) * 130 + 2 * lane];
                float hi = lds_f[(w * 16 + r) * 130 + 2 * lane + 1];
                Yb[(size_t)row * 64 + lane] = pack_bf(lo, hi);
            }
        }
    } else {
        // out_mode 2: bias + softmax over cols < KOUT, f32 output [nrows, KOUT]
        float bb[8];
#pragma unroll
        for (int ct = 0; ct < 8; ct++) bb[ct] = bias[ct * 16 + m16];
        float* Yf = (float*)Y;
#pragma unroll
        for (int r = 0; r < 4; r++) {
            int row = r0 + w * 16 + quad * 4 + r;
            float vv[8];
            float mx = -1e30f;
#pragma unroll
            for (int ct = 0; ct < 8; ct++) {
                int col = ct * 16 + m16;
                vv[ct] = (col < KOUT) ? acc[ct][r] + bb[ct] : -1e30f;
                mx = fmaxf(mx, vv[ct]);
            }
#pragma unroll
            for (int off = 1; off < 16; off <<= 1) mx = fmaxf(mx, __shfl_xor(mx, off));
            float se = 0.f;
#pragma unroll
            for (int ct = 0; ct < 8; ct++) {
                vv[ct] = (vv[ct] > -1e29f) ? __expf(vv[ct] - mx) : 0.f;
                se += vv[ct];
            }
#pragma unroll
            for (int off = 1; off < 16; off <<= 1) se += __shfl_xor(se, off);
            float inv = 1.f / se;
            if (row < nrows) {
#pragma unroll
                for (int ct = 0; ct < 8; ct++) {
                    int col = ct * 16 + m16;
                    if (col < KOUT) Yf[(size_t)row * KOUT + col] = vv[ct] * inv;
                }
            }
        }
    }
}

// ---------------- Aggregate: Ob[i] = pack_bf( sum Hb[src]*dinv[src]*dinv[i] + Hb[i]*dinv^2 + b )
// one wave per node; 4 groups of 16 lanes, each group = 1 edge, lane = uint4 (8 feats).
// 16 edges in flight per iteration; masked tail; butterfly reduce across groups.

__launch_bounds__(256)
__global__ void aggregate_kernel(const uint4* __restrict__ Hb4, const int* __restrict__ csr,
                                 const int* __restrict__ rowptr, const int* __restrict__ deg,
                                 const float* __restrict__ dinv, const float* __restrict__ bias,
                                 unsigned int* __restrict__ Ob, int n, int do_relu) {
    int wid = threadIdx.x >> 6, lane = threadIdx.x & 63;
    int g = lane >> 4, c = lane & 15;
    int i = blockIdx.x * 4 + wid;
    if (i >= n) return;

    float di = dinv[i];
    float acc[8];
    {   // self-loop (counted once: group 0 only)
        uint4 sv = Hb4[(size_t)i * 16 + c];
        float sl = (g == 0) ? di * di : 0.f;
        unsigned int su[4] = {sv.x, sv.y, sv.z, sv.w};
#pragma unroll
        for (int t = 0; t < 4; t++) {
            acc[2 * t]     = bf_lo(su[t]) * sl;
            acc[2 * t + 1] = bf_hi(su[t]) * sl;
        }
    }

    const int* cp = csr + rowptr[i];
    int cnt = deg[i] - 1;
    for (int e = 0; e < cnt; e += 16) {
        int s[4];
        uint4 v[4];
        float wgt[4];
#pragma unroll
        for (int u = 0; u < 4; u++) {
            int idx = e + u * 4 + g;
            s[u] = (idx < cnt) ? cp[idx] : i;
        }
#pragma unroll
        for (int u = 0; u < 4; u++) v[u] = Hb4[(size_t)s[u] * 16 + c];
#pragma unroll
        for (int u = 0; u < 4; u++) {
            int idx = e + u * 4 + g;
            wgt[u] = (idx < cnt) ? dinv[s[u]] * di : 0.f;
        }
#pragma unroll
        for (int u = 0; u < 4; u++) {
            unsigned int uu[4] = {v[u].x, v[u].y, v[u].z, v[u].w};
#pragma unroll
            for (int t = 0; t < 4; t++) {
                acc[2 * t]     = fmaf(bf_lo(uu[t]), wgt[u], acc[2 * t]);
                acc[2 * t + 1] = fmaf(bf_hi(uu[t]), wgt[u], acc[2 * t + 1]);
            }
        }
    }

    // butterfly across the 4 groups (lane bits 4,5)
#pragma unroll
    for (int j = 0; j < 8; j++) {
        acc[j] += __shfl_xor(acc[j], 16);
        acc[j] += __shfl_xor(acc[j], 32);
    }

    // lane (g,c) writes feature pair p = c*4+g (feats 8c+2g, 8c+2g+1)
    float2 bb = ((const float2*)bias)[c * 4 + g];
    float fx = acc[g * 2]     + bb.x;
    float fy = acc[g * 2 + 1] + bb.y;
    if (do_relu) { fx = fmaxf(fx, 0.f); fy = fmaxf(fy, 0.f); }
    Ob[(size_t)i * 64 + c * 4 + g] = pack_bf(fx, fy);
}

// ---------------- launch ----------------

extern "C" void kernel_launch(void* const* d_in, const int* in_sizes, int n_in,
                              void* d_out, int out_size, void* d_ws, size_t ws_size,
                              hipStream_t stream) {
    const float* x  = (const float*)d_in[0];
    const int*   ei = (const int*)d_in[1];     // [2,E] int32
    const float* W1 = (const float*)d_in[2];
    const float* b1 = (const float*)d_in[3];
    const float* W2 = (const float*)d_in[4];
    const float* b2 = (const float*)d_in[5];
    const float* Wa = (const float*)d_in[6];
    const float* ba = (const float*)d_in[7];
    float* out = (float*)d_out;

    int N = in_sizes[0] / D;
    int E = in_sizes[1] / 2;

    int nbuck = (N + 255) >> 8;                       // 196 for N=50000
    int cap = ((E / nbuck) + 2048 + 63) & ~63;        // 10240 here; must be <= BCAP

    char* w = (char*)d_ws;
    size_t off = 0;
    auto carve = [&](size_t bytes) -> void* {
        void* p = w + off;
        off = (off + bytes + 255) & ~(size_t)255;
        return p;
    };
    int*   deg    = (int*)carve((size_t)N * 4);
    float* dinv   = (float*)carve((size_t)N * 4);
    int*   rowptr = (int*)carve((size_t)N * 4);
    int*   bcur   = (int*)carve(256 * 4);
    unsigned int* bdata = (unsigned int*)carve((size_t)nbuck * cap * 4);
    int*   csr    = (int*)carve((size_t)E * 4);
    unsigned short* Wf1 = (unsigned short*)carve(16384 * 2);
    unsigned short* Wf2 = (unsigned short*)carve(16384 * 2);
    unsigned short* WfA = (unsigned short*)carve(16384 * 2);
    float* bpad   = (float*)carve(512);
    unsigned int* HbA = (unsigned int*)carve((size_t)N * 64 * 4);  // bf16 rows, 256 B
    unsigned int* HbB = (unsigned int*)carve((size_t)N * 64 * 4);
    (void)ws_size; (void)n_in; (void)out_size;

    int nbNode4 = (N + 3) / 4;
    int nbGemm = (N + 63) / 64;
    int nbP1 = (E + CHUNK - 1) / CHUNK;

    (void)hipMemsetAsync(bcur, 0, 256 * 4, stream);
    bucket_pass1<<<nbP1, 256, 0, stream>>>(ei, E, nbuck, cap, bcur, bdata);
    bucket_build<<<nbuck, 256, 0, stream>>>(bdata, bcur, cap, deg, dinv, rowptr, csr, N, nbuck);
    prep_frag_kernel<<<192, 256, 0, stream>>>(W1, W2, Wa, ba, Wf1, Wf2, WfA, bpad);

    // layer 1
    gemm_mfma_kernel<<<nbGemm, 256, 0, stream>>>(x, Wf1, nullptr, HbA, N, 0, 1);
    aggregate_kernel<<<nbNode4, 256, 0, stream>>>((const uint4*)HbA, csr, rowptr, deg, dinv, b1, HbB, N, 1);
    // layer 2
    gemm_mfma_kernel<<<nbGemm, 256, 0, stream>>>(HbB, Wf2, nullptr, HbA, N, 1, 1);
    aggregate_kernel<<<nbNode4, 256, 0, stream>>>((const uint4*)HbA, csr, rowptr, deg, dinv, b2, HbB, N, 0);
    // attention + fused softmax -> out
    gemm_mfma_kernel<<<nbGemm, 256, 0, stream>>>(HbB, WfA, bpad, out, N, 1, 2);
}

// Round 9
// 269.365 us; speedup vs baseline: 1.4946x; 1.0298x over previous
//
#include <hip/hip_runtime.h>

#define D 128
#define KOUT 100
#define CHUNK 4096   // edges per pass-1 block

typedef __attribute__((ext_vector_type(8))) short short8;
typedef __attribute__((ext_vector_type(4))) float floatx4;

// ---------------- bf16 pack/unpack helpers ----------------
__device__ inline float bf_lo(unsigned int u) { return __uint_as_float(u << 16); }
__device__ inline float bf_hi(unsigned int u) { return __uint_as_float(u & 0xFFFF0000u); }

__device__ inline unsigned int bf_round(float a) {      // f32 -> bf16 bits (RNE)
    unsigned int ua = __float_as_uint(a);
    return (ua + 0x7FFFu + ((ua >> 16) & 1u)) >> 16;
}
__device__ inline unsigned int pack_bf(float a, float b) {
    return bf_round(a) | (bf_round(b) << 16);
}

// ---------------- CSR build pass 1: bucket radix partition ----------------
// bucket = dst >> 8; packed record: bits[23:0]=src, bits[31:24]=dst&255

__launch_bounds__(256)
__global__ void bucket_pass1(const int* __restrict__ ei, int E, int nbuck, int cap,
                             int* __restrict__ bcur, unsigned int* __restrict__ bdata) {
    __shared__ int hist[256];
    __shared__ int sc[256];
    __shared__ int pfx[256];
    __shared__ int cur[256];
    __shared__ int gbase[256];
    __shared__ unsigned int lbuf[CHUNK];      // 16 KB
    __shared__ unsigned char bkt[CHUNK];      // 4 KB

    int tid = threadIdx.x;
    int base = blockIdx.x * CHUNK;
    int cnt = E - base; if (cnt > CHUNK) cnt = CHUNK;

    hist[tid] = 0;
    __syncthreads();

    int src[CHUNK / 256];
    int dst[CHUNK / 256];
#pragma unroll
    for (int q = 0; q < CHUNK / 256; q++) {
        int li = tid + q * 256;
        if (li < cnt) {
            src[q] = ei[base + li];
            dst[q] = ei[E + base + li];
            atomicAdd(&hist[dst[q] >> 8], 1);
        }
    }
    __syncthreads();

    int v = hist[tid];
    sc[tid] = v;
    __syncthreads();
    for (int off = 1; off < 256; off <<= 1) {
        int t = (tid >= off) ? sc[tid - off] : 0;
        __syncthreads();
        sc[tid] += t;
        __syncthreads();
    }
    int excl = sc[tid] - v;
    pfx[tid] = excl;
    cur[tid] = excl;
    gbase[tid] = 0;
    if (tid < nbuck && v > 0) gbase[tid] = atomicAdd(&bcur[tid], v);
    __syncthreads();

#pragma unroll
    for (int q = 0; q < CHUNK / 256; q++) {
        int li = tid + q * 256;
        if (li < cnt) {
            int b = dst[q] >> 8;
            int p = atomicAdd(&cur[b], 1);
            lbuf[p] = (unsigned int)src[q] | ((unsigned int)(dst[q] & 255) << 24);
            bkt[p] = (unsigned char)b;
        }
    }
    __syncthreads();

    for (int p = tid; p < cnt; p += 256) {
        int b = bkt[p];
        bdata[(size_t)b * cap + gbase[b] + (p - pfx[b])] = lbuf[p];
    }
}

// ---------------- CSR build pass 2 (fused): deg + dinv + rowptr + scatter ----------------
// one block per bucket; bdata read twice (2nd read L2-hot) -> no big LDS, full occupancy.

__launch_bounds__(256)
__global__ void bucket_build(const unsigned int* __restrict__ bdata, const int* __restrict__ bcur,
                             int cap, int* __restrict__ deg, float* __restrict__ dinv,
                             int* __restrict__ rowptr, int* __restrict__ csr, int n, int nbuck) {
    __shared__ int cnts[256];
    __shared__ int sc[256];
    __shared__ int cur[256];
    __shared__ int bbase;

    int b = blockIdx.x, tid = threadIdx.x;
    if (tid == 0) bbase = 0;
    cnts[tid] = 0;
    __syncthreads();

    // sum of bucket counts before b
    int part = 0;
    for (int t = tid; t < b; t += 256) part += bcur[t];
#pragma unroll
    for (int off = 32; off > 0; off >>= 1) part += __shfl_down(part, off);
    if ((tid & 63) == 0 && part != 0) atomicAdd(&bbase, part);

    int cnt = bcur[b];
    const unsigned int* p = bdata + (size_t)b * cap;
    for (int e = tid; e < cnt; e += 256) atomicAdd(&cnts[p[e] >> 24], 1);
    __syncthreads();

    int v = cnts[tid];
    sc[tid] = v;
    __syncthreads();
    for (int off = 1; off < 256; off <<= 1) {
        int t = (tid >= off) ? sc[tid - off] : 0;
        __syncthreads();
        sc[tid] += t;
        __syncthreads();
    }
    int gstart = bbase + (sc[tid] - v);
    int node = b * 256 + tid;
    if (node < n) {
        deg[node] = v + 1;
        dinv[node] = rsqrtf((float)(v + 1));
        rowptr[node] = gstart;
    }
    cur[tid] = gstart;
    __syncthreads();

    for (int e = tid; e < cnt; e += 256) {
        unsigned int u = p[e];
        int pos = atomicAdd(&cur[u >> 24], 1);
        csr[pos] = (int)(u & 0xFFFFFFu);
    }
}

// ---------------- Weight prep + bcur zero + Hb zero-rows ----------------
// Wfrag[(kt*8+ct)*64 + lane][j] = W[kt*32 + (lane>>4)*8 + j][ct*16 + (lane&15)]

__global__ void prep_frag_kernel(const float* __restrict__ W1, const float* __restrict__ W2,
                                 const float* __restrict__ Wa, const float* __restrict__ ba,
                                 unsigned short* __restrict__ Wf1, unsigned short* __restrict__ Wf2,
                                 unsigned short* __restrict__ WfA, float* __restrict__ bpad,
                                 int* __restrict__ bcur,
                                 unsigned int* __restrict__ zrowA, unsigned int* __restrict__ zrowB) {
    int idx = blockIdx.x * blockDim.x + threadIdx.x;
    if (idx < 3 * 16384) {
        int m = idx / 16384;
        int e = idx & 16383;
        int j = e & 7, lane = (e >> 3) & 63, ct = (e >> 9) & 7, kt = e >> 12;
        int k = kt * 32 + (lane >> 4) * 8 + j;
        int col = ct * 16 + (lane & 15);
        float val;
        unsigned short* dst;
        if (m == 0)      { val = W1[k * 128 + col]; dst = Wf1; }
        else if (m == 1) { val = W2[k * 128 + col]; dst = Wf2; }
        else             { val = (col < KOUT) ? Wa[k * KOUT + col] : 0.f; dst = WfA; }
        dst[e] = (unsigned short)bf_round(val);
    }
    if (idx < 128) bpad[idx] = (idx < KOUT) ? ba[idx] : 0.f;
    if (idx < 256) bcur[idx] = 0;
    if (idx < 64) { zrowA[idx] = 0u; zrowB[idx] = 0u; }
}

// ---------------- MFMA GEMM ----------------
// block 256 = 4 waves; tile 64 rows x 128 cols; wave w: rows w*16..+15.
// in_bf16: A-fragments read directly from packed-bf16 global rows.
// out_mode 1: packed-bf16 rows, each row scaled by oscale[row] if given (dinv prescale).
// out_mode 2: +bias, softmax over first KOUT cols, f32 [nrows, KOUT] output.

__launch_bounds__(256)
__global__ void gemm_mfma_kernel(const void* __restrict__ Xin, const unsigned short* __restrict__ Wf,
                                 const float* __restrict__ bias, const float* __restrict__ oscale,
                                 void* __restrict__ Y, int nrows, int in_bf16, int out_mode) {
    __shared__ float lds_f[64 * 130];                      // 33280 B
    unsigned short* lds_h = (unsigned short*)lds_f;
    unsigned int* lds_u = (unsigned int*)lds_f;

    int tid = threadIdx.x;
    int w = tid >> 6, lane = tid & 63;
    int quad = lane >> 4, m16 = lane & 15;
    int r0 = blockIdx.x * 64;

    if (!in_bf16) {
        int row = tid >> 2, cg = tid & 3;
        bool valid = (r0 + row) < nrows;
        const float4* Xr = (const float4*)Xin + (size_t)(r0 + row) * 32 + cg * 8;
#pragma unroll
        for (int j = 0; j < 8; j++) {
            float4 v = valid ? Xr[j] : make_float4(0.f, 0.f, 0.f, 0.f);
            int c = cg * 32 + j * 4;
            lds_u[row * 68 + (c >> 1)]     = pack_bf(v.x, v.y);
            lds_u[row * 68 + (c >> 1) + 1] = pack_bf(v.z, v.w);
        }
        __syncthreads();
    }

    floatx4 acc[8];
#pragma unroll
    for (int ct = 0; ct < 8; ct++) acc[ct] = (floatx4){0.f, 0.f, 0.f, 0.f};

    int arow = r0 + w * 16 + m16;
    if (arow > nrows - 1) arow = nrows - 1;
    const unsigned int* Xb = (const unsigned int*)Xin;

    const short8* Wf8 = (const short8*)Wf;
#pragma unroll
    for (int kt = 0; kt < 4; kt++) {
        short8 a;
        if (in_bf16) {
            a = *(const short8*)(Xb + (size_t)arow * 64 + kt * 16 + quad * 4);
        } else {
            a = *(const short8*)(lds_h + (w * 16 + m16) * 136 + kt * 32 + quad * 8);
        }
#pragma unroll
        for (int ct = 0; ct < 8; ct++) {
            short8 b = Wf8[(kt * 8 + ct) * 64 + lane];
            acc[ct] = __builtin_amdgcn_mfma_f32_16x16x32_bf16(a, b, acc[ct], 0, 0, 0);
        }
    }

    if (out_mode == 1) {
        __syncthreads();   // reuse LDS as f32 out staging [64][130]
#pragma unroll
        for (int ct = 0; ct < 8; ct++) {
#pragma unroll
            for (int r = 0; r < 4; r++) {
                int rl = w * 16 + quad * 4 + r;
                lds_f[rl * 130 + ct * 16 + m16] = acc[ct][r];
            }
        }
        __syncthreads();
        unsigned int* Yb = (unsigned int*)Y;
        for (int r = 0; r < 16; r++) {
            int row = r0 + w * 16 + r;
            if (row < nrows) {
                float sc = oscale ? oscale[row] : 1.f;
                float lo = lds_f[(w * 16 + r) * 130 + 2 * lane] * sc;
                float hi = lds_f[(w * 16 + r) * 130 + 2 * lane + 1] * sc;
                Yb[(size_t)row * 64 + lane] = pack_bf(lo, hi);
            }
        }
    } else {
        // out_mode 2: bias + softmax over cols < KOUT, f32 output [nrows, KOUT]
        float bb[8];
#pragma unroll
        for (int ct = 0; ct < 8; ct++) bb[ct] = bias[ct * 16 + m16];
        float* Yf = (float*)Y;
#pragma unroll
        for (int r = 0; r < 4; r++) {
            int row = r0 + w * 16 + quad * 4 + r;
            float vv[8];
            float mx = -1e30f;
#pragma unroll
            for (int ct = 0; ct < 8; ct++) {
                int col = ct * 16 + m16;
                vv[ct] = (col < KOUT) ? acc[ct][r] + bb[ct] : -1e30f;
                mx = fmaxf(mx, vv[ct]);
            }
#pragma unroll
            for (int off = 1; off < 16; off <<= 1) mx = fmaxf(mx, __shfl_xor(mx, off));
            float se = 0.f;
#pragma unroll
            for (int ct = 0; ct < 8; ct++) {
                vv[ct] = (vv[ct] > -1e29f) ? __expf(vv[ct] - mx) : 0.f;
                se += vv[ct];
            }
#pragma unroll
            for (int off = 1; off < 16; off <<= 1) se += __shfl_xor(se, off);
            float inv = 1.f / se;
            if (row < nrows) {
#pragma unroll
                for (int ct = 0; ct < 8; ct++) {
                    int col = ct * 16 + m16;
                    if (col < KOUT) Yf[(size_t)row * KOUT + col] = vv[ct] * inv;
                }
            }
        }
    }
}

// ---------------- Aggregate (prescaled rows): Ob[i] = bf16( di*(Σ Hb'[src] + Hb'[i]) + b )
// Hb' rows already scaled by dinv[src] (GEMM epilogue). No per-edge weight.
// one wave per node; 4 groups of 16 lanes, group = 1 edge, lane = uint4 (8 feats).
// masked tail points at zero-row index n.

__launch_bounds__(256)
__global__ void aggregate_kernel(const uint4* __restrict__ Hb4, const int* __restrict__ csr,
                                 const int* __restrict__ rowptr, const int* __restrict__ deg,
                                 const float* __restrict__ dinv, const float* __restrict__ bias,
                                 unsigned int* __restrict__ Ob, int n, int do_relu) {
    int wid = threadIdx.x >> 6, lane = threadIdx.x & 63;
    int g = lane >> 4, c = lane & 15;
    int i = blockIdx.x * 4 + wid;
    if (i >= n) return;

    float di = dinv[i];
    float acc[8];
    {   // self term (group 0 only)
        uint4 sv = Hb4[(size_t)i * 16 + c];
        unsigned int su[4] = {sv.x, sv.y, sv.z, sv.w};
        if (g != 0) { su[0] = su[1] = su[2] = su[3] = 0u; }
#pragma unroll
        for (int t = 0; t < 4; t++) {
            acc[2 * t]     = bf_lo(su[t]);
            acc[2 * t + 1] = bf_hi(su[t]);
        }
    }

    const int* cp = csr + rowptr[i];
    int cnt = deg[i] - 1;
    for (int e = 0; e < cnt; e += 16) {
        int s[4];
        uint4 v[4];
#pragma unroll
        for (int u = 0; u < 4; u++) {
            int idx = e + u * 4 + g;
            s[u] = (idx < cnt) ? cp[idx] : n;      // n = zero row
        }
#pragma unroll
        for (int u = 0; u < 4; u++) v[u] = Hb4[(size_t)s[u] * 16 + c];
#pragma unroll
        for (int u = 0; u < 4; u++) {
            unsigned int uu[4] = {v[u].x, v[u].y, v[u].z, v[u].w};
#pragma unroll
            for (int t = 0; t < 4; t++) {
                acc[2 * t]     += bf_lo(uu[t]);
                acc[2 * t + 1] += bf_hi(uu[t]);
            }
        }
    }

    // butterfly across the 4 groups (lane bits 4,5)
#pragma unroll
    for (int j = 0; j < 8; j++) {
        acc[j] += __shfl_xor(acc[j], 16);
        acc[j] += __shfl_xor(acc[j], 32);
    }

    // lane (g,c) writes feature pair p = c*4+g (feats 8c+2g, 8c+2g+1)
    float2 bb = ((const float2*)bias)[c * 4 + g];
    float fx = acc[g * 2]     * di + bb.x;
    float fy = acc[g * 2 + 1] * di + bb.y;
    if (do_relu) { fx = fmaxf(fx, 0.f); fy = fmaxf(fy, 0.f); }
    Ob[(size_t)i * 64 + c * 4 + g] = pack_bf(fx, fy);
}

// ---------------- launch ----------------

extern "C" void kernel_launch(void* const* d_in, const int* in_sizes, int n_in,
                              void* d_out, int out_size, void* d_ws, size_t ws_size,
                              hipStream_t stream) {
    const float* x  = (const float*)d_in[0];
    const int*   ei = (const int*)d_in[1];     // [2,E] int32
    const float* W1 = (const float*)d_in[2];
    const float* b1 = (const float*)d_in[3];
    const float* W2 = (const float*)d_in[4];
    const float* b2 = (const float*)d_in[5];
    const float* Wa = (const float*)d_in[6];
    const float* ba = (const float*)d_in[7];
    float* out = (float*)d_out;

    int N = in_sizes[0] / D;
    int E = in_sizes[1] / 2;

    int nbuck = (N + 255) >> 8;                       // 196 for N=50000
    int cap = ((E / nbuck) + 2048 + 63) & ~63;

    char* w = (char*)d_ws;
    size_t off = 0;
    auto carve = [&](size_t bytes) -> void* {
        void* p = w + off;
        off = (off + bytes + 255) & ~(size_t)255;
        return p;
    };
    int*   deg    = (int*)carve((size_t)N * 4);
    float* dinv   = (float*)carve((size_t)N * 4);
    int*   rowptr = (int*)carve((size_t)N * 4);
    int*   bcur   = (int*)carve(256 * 4);
    unsigned int* bdata = (unsigned int*)carve((size_t)nbuck * cap * 4);
    int*   csr    = (int*)carve((size_t)E * 4);
    unsigned short* Wf1 = (unsigned short*)carve(16384 * 2);
    unsigned short* Wf2 = (unsigned short*)carve(16384 * 2);
    unsigned short* WfA = (unsigned short*)carve(16384 * 2);
    float* bpad   = (float*)carve(512);
    unsigned int* HbA = (unsigned int*)carve((size_t)(N + 1) * 64 * 4);  // +1 zero row
    unsigned int* HbB = (unsigned int*)carve((size_t)(N + 1) * 64 * 4);
    (void)ws_size; (void)n_in; (void)out_size;

    int nbNode4 = (N + 3) / 4;
    int nbGemm = (N + 63) / 64;
    int nbP1 = (E + CHUNK - 1) / CHUNK;

    prep_frag_kernel<<<192, 256, 0, stream>>>(W1, W2, Wa, ba, Wf1, Wf2, WfA, bpad,
                                              bcur, HbA + (size_t)N * 64, HbB + (size_t)N * 64);
    bucket_pass1<<<nbP1, 256, 0, stream>>>(ei, E, nbuck, cap, bcur, bdata);
    bucket_build<<<nbuck, 256, 0, stream>>>(bdata, bcur, cap, deg, dinv, rowptr, csr, N, nbuck);

    // layer 1 (gemm writes bf16(h*dinv) rows)
    gemm_mfma_kernel<<<nbGemm, 256, 0, stream>>>(x, Wf1, nullptr, dinv, HbA, N, 0, 1);
    aggregate_kernel<<<nbNode4, 256, 0, stream>>>((const uint4*)HbA, csr, rowptr, deg, dinv, b1, HbB, N, 1);
    // layer 2
    gemm_mfma_kernel<<<nbGemm, 256, 0, stream>>>(HbB, Wf2, nullptr, dinv, HbA, N, 1, 1);
    aggregate_kernel<<<nbNode4, 256, 0, stream>>>((const uint4*)HbA, csr, rowptr, deg, dinv, b2, HbB, N, 0);
    // attention + fused softmax -> out
    gemm_mfma_kernel<<<nbGemm, 256, 0, stream>>>(HbB, WfA, bpad, nullptr, out, N, 1, 2);
}